// Round 7
// baseline (621.282 us; speedup 1.0000x reference)
//
#include <hip/hip_runtime.h>

#define N_NODES 100000
#define N_EDGES 1600000
#define IN_F 256
#define HID 128
#define OUT_F 48
#define PAD_F 64
#define ALPHA 0.01f
#define K_STEPS 10
#define DROP_SCALE (1.0f / (1.0f + 1e-5f))

#define NBUCK 196      // buckets of 512 rows
#define BCAP 10240     // bucket capacity (mean 8163, 23 sigma headroom)
#define EPB 4096       // edges per bucketing block
#define ROW_MASK_CLR 0xFFFFFFFFFC01FFFFULL  // clears bits 25:17 (local row)

typedef __bf16 v8bf __attribute__((ext_vector_type(8)));
typedef float v4f __attribute__((ext_vector_type(4)));
typedef unsigned long long u64;

static __device__ __forceinline__ __bf16 tobf(float f) { return (__bf16)f; }

// ---------------- weight transpose+convert ---------------------------------
__global__ __launch_bounds__(256) void conv_w(const float* __restrict__ W1,
                                              const float* __restrict__ W2,
                                              __bf16* __restrict__ w1t,
                                              __bf16* __restrict__ w2t) {
  int i = blockIdx.x * 256 + threadIdx.x;
  if (i < HID * IN_F) {
    int n = i >> 8, k = i & 255;
    w1t[i] = tobf(W1[k * HID + n]);
  }
  int j = i - HID * IN_F;
  if (j >= 0 && j < OUT_F * HID) {
    int n = j >> 7, k = j & 127;
    w2t[j] = tobf(W2[k * OUT_F + n]);
  }
}

// ---------------- fused MLP via MFMA -> h0 bf16 [N][64] (cols 48-63 = 0) ---
// LDS ~35 KB -> 4 blocks/CU (vs 65 KB / 2 blocks before)
#define BM 64
__global__ __launch_bounds__(256) void mlp_mfma(
    const float* __restrict__ x, const __bf16* __restrict__ w1t,
    const float* __restrict__ b1, const __bf16* __restrict__ w2t,
    const float* __restrict__ b2, __bf16* __restrict__ h0) {
  __shared__ __bf16 xs[BM][136];   // one 128-wide K-half of x, +8 pad
  __shared__ __bf16 h1s[BM][136];
  __shared__ float b1s[HID];
  __shared__ float b2s[OUT_F];

  const int tid = threadIdx.x;
  const int n0 = blockIdx.x * BM;
  if (tid < HID) b1s[tid] = b1[tid];
  if (tid < OUT_F) b2s[tid] = b2[tid];

  const int wv = tid >> 6;
  const int l = tid & 63;
  const int lm = l & 15;
  const int ko = (l >> 4) * 8;
  const int row = (wv << 4) + lm;

  v4f acc1[8];
#pragma unroll
  for (int nf = 0; nf < 8; nf++) acc1[nf] = (v4f){0.f, 0.f, 0.f, 0.f};

#pragma unroll
  for (int half = 0; half < 2; half++) {
    // stage this K-half of the x tile (fp32 -> bf16): 64 rows x 32 float4
    for (int i = tid; i < BM * 32; i += 256) {
      int r = i >> 5, c4 = i & 31;
      int gr = n0 + r;
      float4 v = make_float4(0.f, 0.f, 0.f, 0.f);
      if (gr < N_NODES)
        v = ((const float4*)(x + (size_t)gr * IN_F + half * 128))[c4];
      __bf16* d = &xs[r][c4 * 4];
      d[0] = tobf(v.x); d[1] = tobf(v.y); d[2] = tobf(v.z); d[3] = tobf(v.w);
    }
    __syncthreads();

    const __bf16* w1base = w1t + (size_t)lm * IN_F + half * 128 + ko;
#pragma unroll
    for (int k0 = 0; k0 < 4; k0++) {
      v8bf a = *(const v8bf*)&xs[row][k0 * 32 + ko];
#pragma unroll
      for (int nf = 0; nf < 8; nf++) {
        v8bf b = *(const v8bf*)(w1base + nf * 16 * IN_F + k0 * 32);
        acc1[nf] = __builtin_amdgcn_mfma_f32_16x16x32_bf16(a, b, acc1[nf], 0, 0, 0);
      }
    }
    __syncthreads();  // xs fully consumed before restaging
  }

  // bias + relu -> h1s (bf16). D frag: row=(l>>4)*4+q, col=lm
#pragma unroll
  for (int nf = 0; nf < 8; nf++) {
    float bb = b1s[nf * 16 + lm];
#pragma unroll
    for (int q = 0; q < 4; q++) {
      int rr = (wv << 4) + (l >> 4) * 4 + q;
      h1s[rr][nf * 16 + lm] = tobf(fmaxf(acc1[nf][q] + bb, 0.f));
    }
  }
  __syncthreads();

  // layer 2: B fragments straight from global w2t (L2-resident, 12 KB)
  v4f acc2[3];
#pragma unroll
  for (int nf = 0; nf < 3; nf++) acc2[nf] = (v4f){0.f, 0.f, 0.f, 0.f};
  const __bf16* w2base = w2t + (size_t)lm * HID + ko;
#pragma unroll
  for (int k0 = 0; k0 < 4; k0++) {
    v8bf a = *(const v8bf*)&h1s[row][k0 * 32 + ko];
#pragma unroll
    for (int nf = 0; nf < 3; nf++) {
      v8bf b = *(const v8bf*)(w2base + nf * 16 * HID + k0 * 32);
      acc2[nf] = __builtin_amdgcn_mfma_f32_16x16x32_bf16(a, b, acc2[nf], 0, 0, 0);
    }
  }
#pragma unroll
  for (int nf = 0; nf < 3; nf++) {
    float bb = b2s[nf * 16 + lm];
#pragma unroll
    for (int q = 0; q < 4; q++) {
      int node = n0 + (wv << 4) + (l >> 4) * 4 + q;
      if (node < N_NODES)
        h0[(size_t)node * PAD_F + nf * 16 + lm] = tobf(acc2[nf][q] + bb);
    }
  }
  for (int i = tid; i < BM * 16; i += 256) {
    int r = i >> 4, c = 48 + (i & 15);
    int node = n0 + r;
    if (node < N_NODES) h0[(size_t)node * PAD_F + c] = (__bf16)0.f;
  }
}

// ---------------- CSR build pass 1: block-aggregated bucket binning ---------
// rec u64: val[63:32] | localrow[25:17] | col[16:0]
__global__ __launch_bounds__(256) void bucket_kernel(
    const int* __restrict__ rows, const int* __restrict__ cols,
    const float* __restrict__ vals, int* __restrict__ bcur,
    u64* __restrict__ brec) {
  __shared__ int lhist[NBUCK];
  __shared__ int lbase[NBUCK];
  const int t = threadIdx.x;
  const int base = blockIdx.x * EPB;

  for (int i = t; i < NBUCK; i += 256) lhist[i] = 0;
  __syncthreads();

  u64 rec[16];
  short bb[16];
  short pp[16];
#pragma unroll
  for (int j = 0; j < 4; j++) {
    int e = base + j * 1024 + t * 4;
    bool ok = e < N_EDGES;
    int4 r4 = ok ? *(const int4*)(rows + e) : make_int4(0, 0, 0, 0);
    int4 c4 = ok ? *(const int4*)(cols + e) : make_int4(0, 0, 0, 0);
    float4 v4 = ok ? *(const float4*)(vals + e) : make_float4(0, 0, 0, 0);
    int rr[4] = {r4.x, r4.y, r4.z, r4.w};
    int cc[4] = {c4.x, c4.y, c4.z, c4.w};
    float vv[4] = {v4.x, v4.y, v4.z, v4.w};
#pragma unroll
    for (int q = 0; q < 4; q++) {
      int idx = j * 4 + q;
      int b = rr[q] >> 9;
      float v = vv[q] * (DROP_SCALE * (1.0f - ALPHA));
      rec[idx] = ((u64)__float_as_uint(v) << 32) |
                 ((u64)(rr[q] & 511) << 17) | (unsigned)cc[q];
      bb[idx] = ok ? (short)b : (short)-1;
      pp[idx] = ok ? (short)atomicAdd(&lhist[b], 1) : (short)0;
    }
  }
  __syncthreads();

  for (int i = t; i < NBUCK; i += 256) {
    int n = lhist[i];
    lbase[i] = (n > 0) ? atomicAdd(&bcur[i * 16], n) : 0;
  }
  __syncthreads();

#pragma unroll
  for (int j = 0; j < 16; j++) {
    if (bb[j] >= 0)
      brec[(size_t)bb[j] * BCAP + lbase[bb[j]] + pp[j]] = rec[j];
  }
}

// ---------------- CSR build: bucket-count exclusive scan --------------------
__global__ __launch_bounds__(256) void bscan_kernel(const int* __restrict__ bcur,
                                                    int* __restrict__ bstart,
                                                    int* __restrict__ rowptr) {
  __shared__ int s[256];
  int t = threadIdx.x;
  int v = (t < NBUCK) ? bcur[t * 16] : 0;
  s[t] = v;
  __syncthreads();
  for (int off = 1; off < 256; off <<= 1) {
    int add = (t >= off) ? s[t - off] : 0;
    __syncthreads();
    s[t] += add;
    __syncthreads();
  }
  if (t < NBUCK) bstart[t] = s[t] - v;
  if (t == 0) rowptr[N_NODES] = N_EDGES;
}

// ---------------- CSR build pass 2: per-bucket LDS counting sort ------------
__global__ __launch_bounds__(512) void csr_kernel(
    const int* __restrict__ bcur, const int* __restrict__ bstart,
    const u64* __restrict__ brec, int* __restrict__ rowptr,
    u64* __restrict__ edges) {
  __shared__ int cnt[512];
  __shared__ int sc[512];
  const int b = blockIdx.x;
  const int t = threadIdx.x;
  const int n = bcur[b * 16];
  const int base = bstart[b];
  const size_t boff = (size_t)b * BCAP;

  cnt[t] = 0;
  __syncthreads();
  for (int i = t; i < n; i += 512)
    atomicAdd(&cnt[(int)((brec[boff + i] >> 17) & 511)], 1);
  __syncthreads();

  int v = cnt[t];
  sc[t] = v;
  __syncthreads();
  for (int off = 1; off < 512; off <<= 1) {
    int add = (t >= off) ? sc[t - off] : 0;
    __syncthreads();
    sc[t] += add;
    __syncthreads();
  }
  int excl = sc[t] - v;
  int grow = b * 512 + t;
  if (grow < N_NODES) rowptr[grow] = base + excl;
  cnt[t] = excl;
  __syncthreads();

  for (int i = t; i < n; i += 512) {
    u64 rec = brec[boff + i];
    int rr = (int)((rec >> 17) & 511);
    int p = atomicAdd(&cnt[rr], 1);
    edges[base + p] = rec & ROW_MASK_CLR;
  }
}

// ---------------- propagation: wave/row, 8 edges x 8 lanes (dwordx4) -------
// edge records are streamed with non-temporal loads to keep L2 for h lines
template <int FINAL>
__global__ __launch_bounds__(256) void prop_kernel(
    const __bf16* __restrict__ hin, __bf16* __restrict__ hout,
    float* __restrict__ fout, const int* __restrict__ rowptr,
    const u64* __restrict__ edges) {
  int wid = (blockIdx.x * 256 + threadIdx.x) >> 6;
  int lane = threadIdx.x & 63;
  if (wid >= N_NODES) return;
  const int g = lane >> 3;
  const int t = lane & 7;
  int s = __builtin_amdgcn_readfirstlane(rowptr[wid]);
  int e = __builtin_amdgcn_readfirstlane(rowptr[wid + 1]);

  float acc[8];
#pragma unroll
  for (int j = 0; j < 8; j++) acc[j] = 0.f;

  if (g == 0) {
    uint4 q = *(const uint4*)(hin + (size_t)wid * PAD_F + t * 8);
    unsigned uu[4] = {q.x, q.y, q.z, q.w};
#pragma unroll
    for (int k = 0; k < 4; k++) {
      acc[2 * k] = ALPHA * __uint_as_float(uu[k] << 16);
      acc[2 * k + 1] = ALPHA * __uint_as_float(uu[k] & 0xffff0000u);
    }
  }

  int i = s + g;
  for (; i + 8 < e; i += 16) {
    u64 r0 = __builtin_nontemporal_load(edges + i);
    u64 r1 = __builtin_nontemporal_load(edges + i + 8);
    int c0 = (int)(r0 & 0xffffffffu);
    int c1 = (int)(r1 & 0xffffffffu);
    float v0 = __uint_as_float((unsigned)(r0 >> 32));
    float v1 = __uint_as_float((unsigned)(r1 >> 32));
    uint4 q0 = *(const uint4*)(hin + (size_t)c0 * PAD_F + t * 8);
    uint4 q1 = *(const uint4*)(hin + (size_t)c1 * PAD_F + t * 8);
    unsigned a0[4] = {q0.x, q0.y, q0.z, q0.w};
    unsigned a1[4] = {q1.x, q1.y, q1.z, q1.w};
#pragma unroll
    for (int k = 0; k < 4; k++) {
      acc[2 * k] = fmaf(v0, __uint_as_float(a0[k] << 16), acc[2 * k]);
      acc[2 * k + 1] = fmaf(v0, __uint_as_float(a0[k] & 0xffff0000u), acc[2 * k + 1]);
    }
#pragma unroll
    for (int k = 0; k < 4; k++) {
      acc[2 * k] = fmaf(v1, __uint_as_float(a1[k] << 16), acc[2 * k]);
      acc[2 * k + 1] = fmaf(v1, __uint_as_float(a1[k] & 0xffff0000u), acc[2 * k + 1]);
    }
  }
  if (i < e) {
    u64 r0 = __builtin_nontemporal_load(edges + i);
    int c0 = (int)(r0 & 0xffffffffu);
    float v0 = __uint_as_float((unsigned)(r0 >> 32));
    uint4 q0 = *(const uint4*)(hin + (size_t)c0 * PAD_F + t * 8);
    unsigned a0[4] = {q0.x, q0.y, q0.z, q0.w};
#pragma unroll
    for (int k = 0; k < 4; k++) {
      acc[2 * k] = fmaf(v0, __uint_as_float(a0[k] << 16), acc[2 * k]);
      acc[2 * k + 1] = fmaf(v0, __uint_as_float(a0[k] & 0xffff0000u), acc[2 * k + 1]);
    }
  }

#pragma unroll
  for (int m = 8; m <= 32; m <<= 1) {
#pragma unroll
    for (int j = 0; j < 8; j++) acc[j] += __shfl_xor(acc[j], m, 64);
  }

  if (g == 0) {
    if (FINAL) {
      if (t < 6) {
        float* dst = fout + (size_t)wid * OUT_F + t * 8;
        v4f lo4 = {acc[0], acc[1], acc[2], acc[3]};
        v4f hi4 = {acc[4], acc[5], acc[6], acc[7]};
        __builtin_nontemporal_store(lo4, (v4f*)dst);
        __builtin_nontemporal_store(hi4, (v4f*)(dst + 4));
      }
    } else {
      unsigned w[4];
#pragma unroll
      for (int k = 0; k < 4; k++) {
        unsigned short lo = __builtin_bit_cast(unsigned short, (__bf16)acc[2 * k]);
        unsigned short hi = __builtin_bit_cast(unsigned short, (__bf16)acc[2 * k + 1]);
        w[k] = ((unsigned)hi << 16) | lo;
      }
      *(uint4*)(hout + (size_t)wid * PAD_F + t * 8) =
          make_uint4(w[0], w[1], w[2], w[3]);
    }
  }
}

// ---------------- launch ----------------------------------------------------
extern "C" void kernel_launch(void* const* d_in, const int* in_sizes, int n_in,
                              void* d_out, int out_size, void* d_ws,
                              size_t ws_size, hipStream_t stream) {
  const float* x = (const float*)d_in[0];
  const int* rows = (const int*)d_in[1];
  const int* cols = (const int*)d_in[2];
  const float* vals = (const float*)d_in[3];
  const float* W1 = (const float*)d_in[4];
  const float* b1 = (const float*)d_in[5];
  const float* W2 = (const float*)d_in[6];
  const float* b2 = (const float*)d_in[7];
  float* out = (float*)d_out;

  char* ws = (char*)d_ws;
  const size_t HA_OFF = 0;                  // 12,800,000
  const size_t HB_OFF = 12800000;           // 12,800,000
  const size_t EDGES_OFF = 25600000;        // 12,800,000
  const size_t BREC_OFF = 38400000;         // 196*10240*8 = 16,056,320
  const size_t ROWPTR_OFF = 54456320;       // 400,128
  const size_t BCUR_OFF = 54856448;         // 196*64 = 12,544
  const size_t BSTART_OFF = 54868992;       // 1,024
  const size_t W1T_OFF = 54870016;          // 65,536
  const size_t W2T_OFF = 54935552;          // 12,288

  __bf16* hA = (__bf16*)(ws + HA_OFF);
  __bf16* hB = (__bf16*)(ws + HB_OFF);
  u64* edges = (u64*)(ws + EDGES_OFF);
  u64* brec = (u64*)(ws + BREC_OFF);
  int* rowptr = (int*)(ws + ROWPTR_OFF);
  int* bcur = (int*)(ws + BCUR_OFF);
  int* bstart = (int*)(ws + BSTART_OFF);
  __bf16* w1t = (__bf16*)(ws + W1T_OFF);
  __bf16* w2t = (__bf16*)(ws + W2T_OFF);

  conv_w<<<(HID * IN_F + OUT_F * HID + 255) / 256, 256, 0, stream>>>(W1, W2,
                                                                     w1t, w2t);
  mlp_mfma<<<(N_NODES + BM - 1) / BM, 256, 0, stream>>>(x, w1t, b1, w2t, b2, hA);

  (void)hipMemsetAsync(bcur, 0, NBUCK * 64, stream);
  bucket_kernel<<<(N_EDGES + EPB - 1) / EPB, 256, 0, stream>>>(rows, cols, vals,
                                                               bcur, brec);
  bscan_kernel<<<1, 256, 0, stream>>>(bcur, bstart, rowptr);
  csr_kernel<<<NBUCK, 512, 0, stream>>>(bcur, bstart, brec, rowptr, edges);

  const int PROP_BLOCKS = (N_NODES * 64 + 255) / 256;
  for (int k = 0; k < K_STEPS - 1; k++) {
    const __bf16* hin = (k & 1) ? hB : hA;
    __bf16* hout = (k & 1) ? hA : hB;
    prop_kernel<0><<<PROP_BLOCKS, 256, 0, stream>>>(hin, hout, nullptr, rowptr,
                                                    edges);
  }
  prop_kernel<1><<<PROP_BLOCKS, 256, 0, stream>>>(hB, nullptr, out, rowptr,
                                                  edges);
}

// Round 8
// 540.048 us; speedup vs baseline: 1.1504x; 1.1504x over previous
//
#include <hip/hip_runtime.h>

#define N_NODES 100000
#define N_EDGES 1600000
#define IN_F 256
#define HID 128
#define OUT_F 48
#define PAD_F 64
#define ALPHA 0.01f
#define K_STEPS 10
#define DROP_SCALE (1.0f / (1.0f + 1e-5f))

#define NBUCK 196      // buckets of 512 rows
#define BCAP 10240     // bucket capacity (mean 8163, 23 sigma headroom)
#define EPB 4096       // edges per bucketing block
#define ROW_MASK_CLR 0xFFFFFFFFFC01FFFFULL  // clears bits 25:17 (local row)

typedef __bf16 v8bf __attribute__((ext_vector_type(8)));
typedef float v4f __attribute__((ext_vector_type(4)));
typedef unsigned long long u64;

static __device__ __forceinline__ __bf16 tobf(float f) { return (__bf16)f; }

// ---------------- weight transpose+convert ---------------------------------
__global__ __launch_bounds__(256) void conv_w(const float* __restrict__ W1,
                                              const float* __restrict__ W2,
                                              __bf16* __restrict__ w1t,
                                              __bf16* __restrict__ w2t) {
  int i = blockIdx.x * 256 + threadIdx.x;
  if (i < HID * IN_F) {
    int n = i >> 8, k = i & 255;
    w1t[i] = tobf(W1[k * HID + n]);
  }
  int j = i - HID * IN_F;
  if (j >= 0 && j < OUT_F * HID) {
    int n = j >> 7, k = j & 127;
    w2t[j] = tobf(W2[k * OUT_F + n]);
  }
}

// ---------------- fused MLP via MFMA -> h0 bf16 [N][64] (cols 48-63 = 0) ---
// A-fragments of x loaded DIRECTLY global->reg (coalesced 128B per 4-lane
// group); no x LDS staging, no pre-MFMA barriers. 100000 = 6250 waves * 16.
__global__ __launch_bounds__(256) void mlp_mfma(
    const float* __restrict__ x, const __bf16* __restrict__ w1t,
    const float* __restrict__ b1, const __bf16* __restrict__ w2t,
    const float* __restrict__ b2, __bf16* __restrict__ h0) {
  __shared__ __bf16 h1s[64][136];  // 17.4 KB

  const int tid = threadIdx.x;
  const int wv = tid >> 6;
  const int l = tid & 63;
  const int lm = l & 15;
  const int ko = (l >> 4) * 8;
  const int gw = blockIdx.x * 4 + wv;  // global wave id (wave-uniform)
  if (gw >= N_NODES / 16) return;      // dead waves drop out of barriers
  const int n0w = gw * 16;
  const int xrow = n0w + lm;           // this lane's x row

  v4f acc1[8];
#pragma unroll
  for (int nf = 0; nf < 8; nf++) acc1[nf] = (v4f){0.f, 0.f, 0.f, 0.f};

  const float* xb = x + (size_t)xrow * IN_F + ko;
#pragma unroll
  for (int kh = 0; kh < 2; kh++) {
    // 8 independent 16B loads in flight (this lane's A data for 4 k-steps)
    float4 xr[8];
#pragma unroll
    for (int k0 = 0; k0 < 4; k0++) {
      const float* p = xb + (kh * 4 + k0) * 32;
      xr[2 * k0] = *(const float4*)p;
      xr[2 * k0 + 1] = *(const float4*)(p + 4);
    }
#pragma unroll
    for (int k0 = 0; k0 < 4; k0++) {
      const float* f0 = (const float*)&xr[2 * k0];
      v8bf a;
#pragma unroll
      for (int j = 0; j < 8; j++) a[j] = tobf(f0[j]);
      const __bf16* w1base = w1t + (size_t)lm * IN_F + (kh * 4 + k0) * 32 + ko;
#pragma unroll
      for (int nf = 0; nf < 8; nf++) {
        v8bf b = *(const v8bf*)(w1base + nf * 16 * IN_F);
        acc1[nf] = __builtin_amdgcn_mfma_f32_16x16x32_bf16(a, b, acc1[nf], 0, 0, 0);
      }
    }
  }

  // bias + relu -> h1s. D frag: col=lm, row=(l>>4)*4+q
#pragma unroll
  for (int nf = 0; nf < 8; nf++) {
    float bb = b1[nf * 16 + lm];
#pragma unroll
    for (int q = 0; q < 4; q++) {
      int rr = (wv << 4) + (l >> 4) * 4 + q;
      h1s[rr][nf * 16 + lm] = tobf(fmaxf(acc1[nf][q] + bb, 0.f));
    }
  }
  __syncthreads();

  // layer 2: A from h1s, B straight from global w2t (L2-resident, 12 KB)
  const int lrow = (wv << 4) + lm;
  v4f acc2[3];
#pragma unroll
  for (int nf = 0; nf < 3; nf++) acc2[nf] = (v4f){0.f, 0.f, 0.f, 0.f};
  const __bf16* w2base = w2t + (size_t)lm * HID + ko;
#pragma unroll
  for (int k0 = 0; k0 < 4; k0++) {
    v8bf a = *(const v8bf*)&h1s[lrow][k0 * 32 + ko];
#pragma unroll
    for (int nf = 0; nf < 3; nf++) {
      v8bf b = *(const v8bf*)(w2base + nf * 16 * HID + k0 * 32);
      acc2[nf] = __builtin_amdgcn_mfma_f32_16x16x32_bf16(a, b, acc2[nf], 0, 0, 0);
    }
  }
#pragma unroll
  for (int nf = 0; nf < 3; nf++) {
    float bb = b2[nf * 16 + lm];
#pragma unroll
    for (int q = 0; q < 4; q++) {
      int node = n0w + (l >> 4) * 4 + q;
      h0[(size_t)node * PAD_F + nf * 16 + lm] = tobf(acc2[nf][q] + bb);
    }
  }
  // zero pad cols 48..63: 16 rows x 32B = 2 uint4 per row, lanes 0..31
  if (l < 32) {
    uint4 z = make_uint4(0, 0, 0, 0);
    *(uint4*)(h0 + (size_t)(n0w + (l >> 1)) * PAD_F + 48 + (l & 1) * 8) = z;
  }
}

// ---------------- CSR build pass 1: block-aggregated bucket binning ---------
// rec u64: val[63:32] | localrow[25:17] | col[16:0]
__global__ __launch_bounds__(256) void bucket_kernel(
    const int* __restrict__ rows, const int* __restrict__ cols,
    const float* __restrict__ vals, int* __restrict__ bcur,
    u64* __restrict__ brec) {
  __shared__ int lhist[NBUCK];
  __shared__ int lbase[NBUCK];
  const int t = threadIdx.x;
  const int base = blockIdx.x * EPB;

  for (int i = t; i < NBUCK; i += 256) lhist[i] = 0;
  __syncthreads();

  u64 rec[16];
  short bb[16];
  short pp[16];
#pragma unroll
  for (int j = 0; j < 4; j++) {
    int e = base + j * 1024 + t * 4;
    bool ok = e < N_EDGES;
    int4 r4 = ok ? *(const int4*)(rows + e) : make_int4(0, 0, 0, 0);
    int4 c4 = ok ? *(const int4*)(cols + e) : make_int4(0, 0, 0, 0);
    float4 v4 = ok ? *(const float4*)(vals + e) : make_float4(0, 0, 0, 0);
    int rr[4] = {r4.x, r4.y, r4.z, r4.w};
    int cc[4] = {c4.x, c4.y, c4.z, c4.w};
    float vv[4] = {v4.x, v4.y, v4.z, v4.w};
#pragma unroll
    for (int q = 0; q < 4; q++) {
      int idx = j * 4 + q;
      int b = rr[q] >> 9;
      float v = vv[q] * (DROP_SCALE * (1.0f - ALPHA));
      rec[idx] = ((u64)__float_as_uint(v) << 32) |
                 ((u64)(rr[q] & 511) << 17) | (unsigned)cc[q];
      bb[idx] = ok ? (short)b : (short)-1;
      pp[idx] = ok ? (short)atomicAdd(&lhist[b], 1) : (short)0;
    }
  }
  __syncthreads();

  for (int i = t; i < NBUCK; i += 256) {
    int n = lhist[i];
    lbase[i] = (n > 0) ? atomicAdd(&bcur[i * 16], n) : 0;
  }
  __syncthreads();

#pragma unroll
  for (int j = 0; j < 16; j++) {
    if (bb[j] >= 0)
      brec[(size_t)bb[j] * BCAP + lbase[bb[j]] + pp[j]] = rec[j];
  }
}

// ---------------- CSR build: bucket-count exclusive scan --------------------
__global__ __launch_bounds__(256) void bscan_kernel(const int* __restrict__ bcur,
                                                    int* __restrict__ bstart,
                                                    int* __restrict__ rowptr) {
  __shared__ int s[256];
  int t = threadIdx.x;
  int v = (t < NBUCK) ? bcur[t * 16] : 0;
  s[t] = v;
  __syncthreads();
  for (int off = 1; off < 256; off <<= 1) {
    int add = (t >= off) ? s[t - off] : 0;
    __syncthreads();
    s[t] += add;
    __syncthreads();
  }
  if (t < NBUCK) bstart[t] = s[t] - v;
  if (t == 0) rowptr[N_NODES] = N_EDGES;
}

// ---------------- CSR build pass 2: per-bucket LDS counting sort ------------
__global__ __launch_bounds__(512) void csr_kernel(
    const int* __restrict__ bcur, const int* __restrict__ bstart,
    const u64* __restrict__ brec, int* __restrict__ rowptr,
    u64* __restrict__ edges) {
  __shared__ int cnt[512];
  __shared__ int sc[512];
  const int b = blockIdx.x;
  const int t = threadIdx.x;
  const int n = bcur[b * 16];
  const int base = bstart[b];
  const size_t boff = (size_t)b * BCAP;

  cnt[t] = 0;
  __syncthreads();
  for (int i = t; i < n; i += 512)
    atomicAdd(&cnt[(int)((brec[boff + i] >> 17) & 511)], 1);
  __syncthreads();

  int v = cnt[t];
  sc[t] = v;
  __syncthreads();
  for (int off = 1; off < 512; off <<= 1) {
    int add = (t >= off) ? sc[t - off] : 0;
    __syncthreads();
    sc[t] += add;
    __syncthreads();
  }
  int excl = sc[t] - v;
  int grow = b * 512 + t;
  if (grow < N_NODES) rowptr[grow] = base + excl;
  cnt[t] = excl;
  __syncthreads();

  for (int i = t; i < n; i += 512) {
    u64 rec = brec[boff + i];
    int rr = (int)((rec >> 17) & 511);
    int p = atomicAdd(&cnt[rr], 1);
    edges[base + p] = rec & ROW_MASK_CLR;
  }
}

// ---------------- propagation: wave/row, 8 edges x 8 lanes (dwordx4) -------
template <int FINAL>
__global__ __launch_bounds__(256) void prop_kernel(
    const __bf16* __restrict__ hin, __bf16* __restrict__ hout,
    float* __restrict__ fout, const int* __restrict__ rowptr,
    const u64* __restrict__ edges) {
  int wid = (blockIdx.x * 256 + threadIdx.x) >> 6;
  int lane = threadIdx.x & 63;
  if (wid >= N_NODES) return;
  const int g = lane >> 3;
  const int t = lane & 7;
  int s = __builtin_amdgcn_readfirstlane(rowptr[wid]);
  int e = __builtin_amdgcn_readfirstlane(rowptr[wid + 1]);

  float acc[8];
#pragma unroll
  for (int j = 0; j < 8; j++) acc[j] = 0.f;

  if (g == 0) {
    uint4 q = *(const uint4*)(hin + (size_t)wid * PAD_F + t * 8);
    unsigned uu[4] = {q.x, q.y, q.z, q.w};
#pragma unroll
    for (int k = 0; k < 4; k++) {
      acc[2 * k] = ALPHA * __uint_as_float(uu[k] << 16);
      acc[2 * k + 1] = ALPHA * __uint_as_float(uu[k] & 0xffff0000u);
    }
  }

  int i = s + g;
  for (; i + 8 < e; i += 16) {
    u64 r0 = edges[i];
    u64 r1 = edges[i + 8];
    int c0 = (int)(r0 & 0xffffffffu);
    int c1 = (int)(r1 & 0xffffffffu);
    float v0 = __uint_as_float((unsigned)(r0 >> 32));
    float v1 = __uint_as_float((unsigned)(r1 >> 32));
    uint4 q0 = *(const uint4*)(hin + (size_t)c0 * PAD_F + t * 8);
    uint4 q1 = *(const uint4*)(hin + (size_t)c1 * PAD_F + t * 8);
    unsigned a0[4] = {q0.x, q0.y, q0.z, q0.w};
    unsigned a1[4] = {q1.x, q1.y, q1.z, q1.w};
#pragma unroll
    for (int k = 0; k < 4; k++) {
      acc[2 * k] = fmaf(v0, __uint_as_float(a0[k] << 16), acc[2 * k]);
      acc[2 * k + 1] = fmaf(v0, __uint_as_float(a0[k] & 0xffff0000u), acc[2 * k + 1]);
    }
#pragma unroll
    for (int k = 0; k < 4; k++) {
      acc[2 * k] = fmaf(v1, __uint_as_float(a1[k] << 16), acc[2 * k]);
      acc[2 * k + 1] = fmaf(v1, __uint_as_float(a1[k] & 0xffff0000u), acc[2 * k + 1]);
    }
  }
  if (i < e) {
    u64 r0 = edges[i];
    int c0 = (int)(r0 & 0xffffffffu);
    float v0 = __uint_as_float((unsigned)(r0 >> 32));
    uint4 q0 = *(const uint4*)(hin + (size_t)c0 * PAD_F + t * 8);
    unsigned a0[4] = {q0.x, q0.y, q0.z, q0.w};
#pragma unroll
    for (int k = 0; k < 4; k++) {
      acc[2 * k] = fmaf(v0, __uint_as_float(a0[k] << 16), acc[2 * k]);
      acc[2 * k + 1] = fmaf(v0, __uint_as_float(a0[k] & 0xffff0000u), acc[2 * k + 1]);
    }
  }

#pragma unroll
  for (int m = 8; m <= 32; m <<= 1) {
#pragma unroll
    for (int j = 0; j < 8; j++) acc[j] += __shfl_xor(acc[j], m, 64);
  }

  if (g == 0) {
    if (FINAL) {
      if (t < 6) {
        float* dst = fout + (size_t)wid * OUT_F + t * 8;
        v4f lo4 = {acc[0], acc[1], acc[2], acc[3]};
        v4f hi4 = {acc[4], acc[5], acc[6], acc[7]};
        __builtin_nontemporal_store(lo4, (v4f*)dst);
        __builtin_nontemporal_store(hi4, (v4f*)(dst + 4));
      }
    } else {
      unsigned w[4];
#pragma unroll
      for (int k = 0; k < 4; k++) {
        unsigned short lo = __builtin_bit_cast(unsigned short, (__bf16)acc[2 * k]);
        unsigned short hi = __builtin_bit_cast(unsigned short, (__bf16)acc[2 * k + 1]);
        w[k] = ((unsigned)hi << 16) | lo;
      }
      *(uint4*)(hout + (size_t)wid * PAD_F + t * 8) =
          make_uint4(w[0], w[1], w[2], w[3]);
    }
  }
}

// ---------------- launch ----------------------------------------------------
extern "C" void kernel_launch(void* const* d_in, const int* in_sizes, int n_in,
                              void* d_out, int out_size, void* d_ws,
                              size_t ws_size, hipStream_t stream) {
  const float* x = (const float*)d_in[0];
  const int* rows = (const int*)d_in[1];
  const int* cols = (const int*)d_in[2];
  const float* vals = (const float*)d_in[3];
  const float* W1 = (const float*)d_in[4];
  const float* b1 = (const float*)d_in[5];
  const float* W2 = (const float*)d_in[6];
  const float* b2 = (const float*)d_in[7];
  float* out = (float*)d_out;

  char* ws = (char*)d_ws;
  const size_t HA_OFF = 0;                  // 12,800,000
  const size_t HB_OFF = 12800000;           // 12,800,000
  const size_t EDGES_OFF = 25600000;        // 12,800,000
  const size_t BREC_OFF = 38400000;         // 196*10240*8 = 16,056,320
  const size_t ROWPTR_OFF = 54456320;       // 400,128
  const size_t BCUR_OFF = 54856448;         // 196*64 = 12,544
  const size_t BSTART_OFF = 54868992;       // 1,024
  const size_t W1T_OFF = 54870016;          // 65,536
  const size_t W2T_OFF = 54935552;          // 12,288

  __bf16* hA = (__bf16*)(ws + HA_OFF);
  __bf16* hB = (__bf16*)(ws + HB_OFF);
  u64* edges = (u64*)(ws + EDGES_OFF);
  u64* brec = (u64*)(ws + BREC_OFF);
  int* rowptr = (int*)(ws + ROWPTR_OFF);
  int* bcur = (int*)(ws + BCUR_OFF);
  int* bstart = (int*)(ws + BSTART_OFF);
  __bf16* w1t = (__bf16*)(ws + W1T_OFF);
  __bf16* w2t = (__bf16*)(ws + W2T_OFF);

  conv_w<<<(HID * IN_F + OUT_F * HID + 255) / 256, 256, 0, stream>>>(W1, W2,
                                                                     w1t, w2t);
  mlp_mfma<<<(N_NODES / 16 + 3) / 4, 256, 0, stream>>>(x, w1t, b1, w2t, b2, hA);

  (void)hipMemsetAsync(bcur, 0, NBUCK * 64, stream);
  bucket_kernel<<<(N_EDGES + EPB - 1) / EPB, 256, 0, stream>>>(rows, cols, vals,
                                                               bcur, brec);
  bscan_kernel<<<1, 256, 0, stream>>>(bcur, bstart, rowptr);
  csr_kernel<<<NBUCK, 512, 0, stream>>>(bcur, bstart, brec, rowptr, edges);

  const int PROP_BLOCKS = (N_NODES * 64 + 255) / 256;
  for (int k = 0; k < K_STEPS - 1; k++) {
    const __bf16* hin = (k & 1) ? hB : hA;
    __bf16* hout = (k & 1) ? hA : hB;
    prop_kernel<0><<<PROP_BLOCKS, 256, 0, stream>>>(hin, hout, nullptr, rowptr,
                                                    edges);
  }
  prop_kernel<1><<<PROP_BLOCKS, 256, 0, stream>>>(hB, nullptr, out, rowptr,
                                                  edges);
}

// Round 9
// 526.153 us; speedup vs baseline: 1.1808x; 1.0264x over previous
//
#include <hip/hip_runtime.h>

#define N_NODES 100000
#define N_EDGES 1600000
#define IN_F 256
#define HID 128
#define OUT_F 48
#define PAD_F 64
#define ALPHA 0.01f
#define K_STEPS 10
#define DROP_SCALE (1.0f / (1.0f + 1e-5f))

#define NBUCK 196      // buckets of 512 rows
#define BCAP 10240     // bucket capacity (mean 8163, 23 sigma headroom)
#define EPB 4096       // edges per bucketing block
#define ROW_MASK_CLR 0xFFFFFFFFFC01FFFFULL  // clears bits 25:17 (local row)

#define MLP_BLOCKS ((N_NODES / 16 + 3) / 4)          // 1563
#define BUCKET_BLOCKS ((N_EDGES + EPB - 1) / EPB)    // 391

typedef __bf16 v8bf __attribute__((ext_vector_type(8)));
typedef float v4f __attribute__((ext_vector_type(4)));
typedef unsigned long long u64;

static __device__ __forceinline__ __bf16 tobf(float f) { return (__bf16)f; }

// ---------------- weight transpose+convert ---------------------------------
__global__ __launch_bounds__(256) void conv_w(const float* __restrict__ W1,
                                              const float* __restrict__ W2,
                                              __bf16* __restrict__ w1t,
                                              __bf16* __restrict__ w2t) {
  int i = blockIdx.x * 256 + threadIdx.x;
  if (i < HID * IN_F) {
    int n = i >> 8, k = i & 255;
    w1t[i] = tobf(W1[k * HID + n]);
  }
  int j = i - HID * IN_F;
  if (j >= 0 && j < OUT_F * HID) {
    int n = j >> 7, k = j & 127;
    w2t[j] = tobf(W2[k * OUT_F + n]);
  }
}

// ---------------- fused: MLP (blocks 0..MLP_BLOCKS-1) + bucket binning -----
// MLP: A-fragments of x loaded DIRECTLY global->reg, whole row prefetched
// (16 float4 in flight per lane). Bucket: block-aggregated binning, hides
// inside the MLP's memory latency on the same CUs.
__global__ __launch_bounds__(256, 4) void fused_mlp_bucket(
    const float* __restrict__ x, const __bf16* __restrict__ w1t,
    const float* __restrict__ b1, const __bf16* __restrict__ w2t,
    const float* __restrict__ b2, __bf16* __restrict__ h0,
    const int* __restrict__ rows, const int* __restrict__ cols,
    const float* __restrict__ vals, int* __restrict__ bcur,
    u64* __restrict__ brec) {
  __shared__ __bf16 h1s[64][136];  // 17.4 KB (mlp path)
  __shared__ int lhist[NBUCK];     // bucket path
  __shared__ int lbase[NBUCK];

  const int tid = threadIdx.x;

  if (blockIdx.x < MLP_BLOCKS) {
    // ======================= MLP path =======================
    const int wv = tid >> 6;
    const int l = tid & 63;
    const int lm = l & 15;
    const int ko = (l >> 4) * 8;
    const int gw = blockIdx.x * 4 + wv;
    if (gw >= N_NODES / 16) return;
    const int n0w = gw * 16;
    const int xrow = n0w + lm;

    // prefetch the lane's whole x row slice: 16 x float4 = 256B in flight
    const float* xb = x + (size_t)xrow * IN_F + ko;
    float4 xr[16];
#pragma unroll
    for (int k0 = 0; k0 < 8; k0++) {
      xr[2 * k0] = *(const float4*)(xb + k0 * 32);
      xr[2 * k0 + 1] = *(const float4*)(xb + k0 * 32 + 4);
    }

    v4f acc1[8];
#pragma unroll
    for (int nf = 0; nf < 8; nf++) acc1[nf] = (v4f){0.f, 0.f, 0.f, 0.f};

#pragma unroll
    for (int k0 = 0; k0 < 8; k0++) {
      const float* f0 = (const float*)&xr[2 * k0];
      v8bf a;
#pragma unroll
      for (int j = 0; j < 8; j++) a[j] = tobf(f0[j]);
      const __bf16* w1base = w1t + (size_t)lm * IN_F + k0 * 32 + ko;
#pragma unroll
      for (int nf = 0; nf < 8; nf++) {
        v8bf b = *(const v8bf*)(w1base + nf * 16 * IN_F);
        acc1[nf] = __builtin_amdgcn_mfma_f32_16x16x32_bf16(a, b, acc1[nf], 0, 0, 0);
      }
    }

    // bias + relu -> h1s. D frag: col=lm, row=(l>>4)*4+q
#pragma unroll
    for (int nf = 0; nf < 8; nf++) {
      float bb = b1[nf * 16 + lm];
#pragma unroll
      for (int q = 0; q < 4; q++) {
        int rr = (wv << 4) + (l >> 4) * 4 + q;
        h1s[rr][nf * 16 + lm] = tobf(fmaxf(acc1[nf][q] + bb, 0.f));
      }
    }
    __syncthreads();

    // layer 2: A from h1s, B straight from global w2t (L2-resident)
    const int lrow = (wv << 4) + lm;
    v4f acc2[3];
#pragma unroll
    for (int nf = 0; nf < 3; nf++) acc2[nf] = (v4f){0.f, 0.f, 0.f, 0.f};
    const __bf16* w2base = w2t + (size_t)lm * HID + ko;
#pragma unroll
    for (int k0 = 0; k0 < 4; k0++) {
      v8bf a = *(const v8bf*)&h1s[lrow][k0 * 32 + ko];
#pragma unroll
      for (int nf = 0; nf < 3; nf++) {
        v8bf b = *(const v8bf*)(w2base + nf * 16 * HID + k0 * 32);
        acc2[nf] = __builtin_amdgcn_mfma_f32_16x16x32_bf16(a, b, acc2[nf], 0, 0, 0);
      }
    }
#pragma unroll
    for (int nf = 0; nf < 3; nf++) {
      float bb = b2[nf * 16 + lm];
#pragma unroll
      for (int q = 0; q < 4; q++) {
        int node = n0w + (l >> 4) * 4 + q;
        h0[(size_t)node * PAD_F + nf * 16 + lm] = tobf(acc2[nf][q] + bb);
      }
    }
    // zero pad cols 48..63
    if (l < 32) {
      uint4 z = make_uint4(0, 0, 0, 0);
      *(uint4*)(h0 + (size_t)(n0w + (l >> 1)) * PAD_F + 48 + (l & 1) * 8) = z;
    }
  } else {
    // ======================= bucket path =======================
    const int bid = blockIdx.x - MLP_BLOCKS;
    const int base = bid * EPB;

    for (int i = tid; i < NBUCK; i += 256) lhist[i] = 0;
    __syncthreads();

    u64 rec[16];
    short bb[16];
    short pp[16];
#pragma unroll
    for (int j = 0; j < 4; j++) {
      int e = base + j * 1024 + tid * 4;
      bool ok = e < N_EDGES;
      int4 r4 = ok ? *(const int4*)(rows + e) : make_int4(0, 0, 0, 0);
      int4 c4 = ok ? *(const int4*)(cols + e) : make_int4(0, 0, 0, 0);
      float4 v4 = ok ? *(const float4*)(vals + e) : make_float4(0, 0, 0, 0);
      int rr[4] = {r4.x, r4.y, r4.z, r4.w};
      int cc[4] = {c4.x, c4.y, c4.z, c4.w};
      float vv[4] = {v4.x, v4.y, v4.z, v4.w};
#pragma unroll
      for (int q = 0; q < 4; q++) {
        int idx = j * 4 + q;
        int b = rr[q] >> 9;
        float v = vv[q] * (DROP_SCALE * (1.0f - ALPHA));
        rec[idx] = ((u64)__float_as_uint(v) << 32) |
                   ((u64)(rr[q] & 511) << 17) | (unsigned)cc[q];
        bb[idx] = ok ? (short)b : (short)-1;
        pp[idx] = ok ? (short)atomicAdd(&lhist[b], 1) : (short)0;
      }
    }
    __syncthreads();

    for (int i = tid; i < NBUCK; i += 256) {
      int n = lhist[i];
      lbase[i] = (n > 0) ? atomicAdd(&bcur[i * 16], n) : 0;
    }
    __syncthreads();

#pragma unroll
    for (int j = 0; j < 16; j++) {
      if (bb[j] >= 0)
        brec[(size_t)bb[j] * BCAP + lbase[bb[j]] + pp[j]] = rec[j];
    }
  }
}

// ---------------- CSR build: bucket-count exclusive scan --------------------
__global__ __launch_bounds__(256) void bscan_kernel(const int* __restrict__ bcur,
                                                    int* __restrict__ bstart,
                                                    int* __restrict__ rowptr) {
  __shared__ int s[256];
  int t = threadIdx.x;
  int v = (t < NBUCK) ? bcur[t * 16] : 0;
  s[t] = v;
  __syncthreads();
  for (int off = 1; off < 256; off <<= 1) {
    int add = (t >= off) ? s[t - off] : 0;
    __syncthreads();
    s[t] += add;
    __syncthreads();
  }
  if (t < NBUCK) bstart[t] = s[t] - v;
  if (t == 0) rowptr[N_NODES] = N_EDGES;
}

// ---------------- CSR build pass 2: per-bucket LDS counting sort ------------
__global__ __launch_bounds__(512) void csr_kernel(
    const int* __restrict__ bcur, const int* __restrict__ bstart,
    const u64* __restrict__ brec, int* __restrict__ rowptr,
    u64* __restrict__ edges) {
  __shared__ int cnt[512];
  __shared__ int sc[512];
  const int b = blockIdx.x;
  const int t = threadIdx.x;
  const int n = bcur[b * 16];
  const int base = bstart[b];
  const size_t boff = (size_t)b * BCAP;

  cnt[t] = 0;
  __syncthreads();
  for (int i = t; i < n; i += 512)
    atomicAdd(&cnt[(int)((brec[boff + i] >> 17) & 511)], 1);
  __syncthreads();

  int v = cnt[t];
  sc[t] = v;
  __syncthreads();
  for (int off = 1; off < 512; off <<= 1) {
    int add = (t >= off) ? sc[t - off] : 0;
    __syncthreads();
    sc[t] += add;
    __syncthreads();
  }
  int excl = sc[t] - v;
  int grow = b * 512 + t;
  if (grow < N_NODES) rowptr[grow] = base + excl;
  cnt[t] = excl;
  __syncthreads();

  for (int i = t; i < n; i += 512) {
    u64 rec = brec[boff + i];
    int rr = (int)((rec >> 17) & 511);
    int p = atomicAdd(&cnt[rr], 1);
    edges[base + p] = rec & ROW_MASK_CLR;
  }
}

// ---------------- propagation: wave/row, 8 edges x 8 lanes (dwordx4) -------
template <int FINAL>
__global__ __launch_bounds__(256) void prop_kernel(
    const __bf16* __restrict__ hin, __bf16* __restrict__ hout,
    float* __restrict__ fout, const int* __restrict__ rowptr,
    const u64* __restrict__ edges) {
  int wid = (blockIdx.x * 256 + threadIdx.x) >> 6;
  int lane = threadIdx.x & 63;
  if (wid >= N_NODES) return;
  const int g = lane >> 3;
  const int t = lane & 7;
  int s = __builtin_amdgcn_readfirstlane(rowptr[wid]);
  int e = __builtin_amdgcn_readfirstlane(rowptr[wid + 1]);

  float acc[8];
#pragma unroll
  for (int j = 0; j < 8; j++) acc[j] = 0.f;

  if (g == 0) {
    uint4 q = *(const uint4*)(hin + (size_t)wid * PAD_F + t * 8);
    unsigned uu[4] = {q.x, q.y, q.z, q.w};
#pragma unroll
    for (int k = 0; k < 4; k++) {
      acc[2 * k] = ALPHA * __uint_as_float(uu[k] << 16);
      acc[2 * k + 1] = ALPHA * __uint_as_float(uu[k] & 0xffff0000u);
    }
  }

  int i = s + g;
  for (; i + 8 < e; i += 16) {
    u64 r0 = edges[i];
    u64 r1 = edges[i + 8];
    int c0 = (int)(r0 & 0xffffffffu);
    int c1 = (int)(r1 & 0xffffffffu);
    float v0 = __uint_as_float((unsigned)(r0 >> 32));
    float v1 = __uint_as_float((unsigned)(r1 >> 32));
    uint4 q0 = *(const uint4*)(hin + (size_t)c0 * PAD_F + t * 8);
    uint4 q1 = *(const uint4*)(hin + (size_t)c1 * PAD_F + t * 8);
    unsigned a0[4] = {q0.x, q0.y, q0.z, q0.w};
    unsigned a1[4] = {q1.x, q1.y, q1.z, q1.w};
#pragma unroll
    for (int k = 0; k < 4; k++) {
      acc[2 * k] = fmaf(v0, __uint_as_float(a0[k] << 16), acc[2 * k]);
      acc[2 * k + 1] = fmaf(v0, __uint_as_float(a0[k] & 0xffff0000u), acc[2 * k + 1]);
    }
#pragma unroll
    for (int k = 0; k < 4; k++) {
      acc[2 * k] = fmaf(v1, __uint_as_float(a1[k] << 16), acc[2 * k]);
      acc[2 * k + 1] = fmaf(v1, __uint_as_float(a1[k] & 0xffff0000u), acc[2 * k + 1]);
    }
  }
  if (i < e) {
    u64 r0 = edges[i];
    int c0 = (int)(r0 & 0xffffffffu);
    float v0 = __uint_as_float((unsigned)(r0 >> 32));
    uint4 q0 = *(const uint4*)(hin + (size_t)c0 * PAD_F + t * 8);
    unsigned a0[4] = {q0.x, q0.y, q0.z, q0.w};
#pragma unroll
    for (int k = 0; k < 4; k++) {
      acc[2 * k] = fmaf(v0, __uint_as_float(a0[k] << 16), acc[2 * k]);
      acc[2 * k + 1] = fmaf(v0, __uint_as_float(a0[k] & 0xffff0000u), acc[2 * k + 1]);
    }
  }

#pragma unroll
  for (int m = 8; m <= 32; m <<= 1) {
#pragma unroll
    for (int j = 0; j < 8; j++) acc[j] += __shfl_xor(acc[j], m, 64);
  }

  if (g == 0) {
    if (FINAL) {
      if (t < 6) {
        float* dst = fout + (size_t)wid * OUT_F + t * 8;
        v4f lo4 = {acc[0], acc[1], acc[2], acc[3]};
        v4f hi4 = {acc[4], acc[5], acc[6], acc[7]};
        __builtin_nontemporal_store(lo4, (v4f*)dst);
        __builtin_nontemporal_store(hi4, (v4f*)(dst + 4));
      }
    } else {
      unsigned w[4];
#pragma unroll
      for (int k = 0; k < 4; k++) {
        unsigned short lo = __builtin_bit_cast(unsigned short, (__bf16)acc[2 * k]);
        unsigned short hi = __builtin_bit_cast(unsigned short, (__bf16)acc[2 * k + 1]);
        w[k] = ((unsigned)hi << 16) | lo;
      }
      *(uint4*)(hout + (size_t)wid * PAD_F + t * 8) =
          make_uint4(w[0], w[1], w[2], w[3]);
    }
  }
}

// ---------------- launch ----------------------------------------------------
extern "C" void kernel_launch(void* const* d_in, const int* in_sizes, int n_in,
                              void* d_out, int out_size, void* d_ws,
                              size_t ws_size, hipStream_t stream) {
  const float* x = (const float*)d_in[0];
  const int* rows = (const int*)d_in[1];
  const int* cols = (const int*)d_in[2];
  const float* vals = (const float*)d_in[3];
  const float* W1 = (const float*)d_in[4];
  const float* b1 = (const float*)d_in[5];
  const float* W2 = (const float*)d_in[6];
  const float* b2 = (const float*)d_in[7];
  float* out = (float*)d_out;

  char* ws = (char*)d_ws;
  const size_t HA_OFF = 0;                  // 12,800,000
  const size_t HB_OFF = 12800000;           // 12,800,000
  const size_t EDGES_OFF = 25600000;        // 12,800,000
  const size_t BREC_OFF = 38400000;         // 196*10240*8 = 16,056,320
  const size_t ROWPTR_OFF = 54456320;       // 400,128
  const size_t BCUR_OFF = 54856448;         // 196*64 = 12,544
  const size_t BSTART_OFF = 54868992;       // 1,024
  const size_t W1T_OFF = 54870016;          // 65,536
  const size_t W2T_OFF = 54935552;          // 12,288

  __bf16* hA = (__bf16*)(ws + HA_OFF);
  __bf16* hB = (__bf16*)(ws + HB_OFF);
  u64* edges = (u64*)(ws + EDGES_OFF);
  u64* brec = (u64*)(ws + BREC_OFF);
  int* rowptr = (int*)(ws + ROWPTR_OFF);
  int* bcur = (int*)(ws + BCUR_OFF);
  int* bstart = (int*)(ws + BSTART_OFF);
  __bf16* w1t = (__bf16*)(ws + W1T_OFF);
  __bf16* w2t = (__bf16*)(ws + W2T_OFF);

  conv_w<<<(HID * IN_F + OUT_F * HID + 255) / 256, 256, 0, stream>>>(W1, W2,
                                                                     w1t, w2t);
  (void)hipMemsetAsync(bcur, 0, NBUCK * 64, stream);

  fused_mlp_bucket<<<MLP_BLOCKS + BUCKET_BLOCKS, 256, 0, stream>>>(
      x, w1t, b1, w2t, b2, hA, rows, cols, vals, bcur, brec);

  bscan_kernel<<<1, 256, 0, stream>>>(bcur, bstart, rowptr);
  csr_kernel<<<NBUCK, 512, 0, stream>>>(bcur, bstart, brec, rowptr, edges);

  const int PROP_BLOCKS = (N_NODES * 64 + 255) / 256;
  for (int k = 0; k < K_STEPS - 1; k++) {
    const __bf16* hin = (k & 1) ? hB : hA;
    __bf16* hout = (k & 1) ? hA : hB;
    prop_kernel<0><<<PROP_BLOCKS, 256, 0, stream>>>(hin, hout, nullptr, rowptr,
                                                    edges);
  }
  prop_kernel<1><<<PROP_BLOCKS, 256, 0, stream>>>(hB, nullptr, out, rowptr,
                                                  edges);
}